// Round 1
// baseline (1635.911 us; speedup 1.0000x reference)
//
#include <hip/hip_runtime.h>
#include <hip/hip_bf16.h>
#include <math.h>

#define BNEPS 1e-5f
#define BDIM_B 128
#define CDIM 512
#define SS 121
#define KK 9
#define MROWS (BDIM_B * SS)   // 15488

// ---------------------------------------------------------------------------
// Tiled fp32 GEMM: Y[m,n] = act( (sum_k X[m,k] * W[n,k] + bias[n]) * bnscale[n] + bnbias[n] )
// XMODE 0: X[m,k] = xsrc[b*Kd*121 + k*121 + p], b=m/121, p=m%121  (BCHW conv1x1)
// XMODE 1: X[m,k] = xsrc[m*Kd + k]                                 (row-major)
// ATOM   : instead of storing Y[m][N], atomicAdd into Y[(m%121)*N + n] (batch sum)
// ---------------------------------------------------------------------------
template<int XMODE, bool ATOM>
__global__ __launch_bounds__(256)
void gemm_bn_relu(const float* __restrict__ X, const float* __restrict__ W,
                  const float* __restrict__ bias, const float* __restrict__ g,
                  const float* __restrict__ bb, float* __restrict__ Y,
                  int M, int N, int Kd)
{
    __shared__ float Xs[16][65];
    __shared__ float Ws[16][65];
    const int tid = threadIdx.x;
    const int bm = blockIdx.x * 64;
    const int bn = blockIdx.y * 64;
    const int tm = (tid / 16) * 4;
    const int tn = (tid % 16) * 4;
    float acc[4][4] = {};

    // X-load index precompute
    int xb = 0, xp = 0;
    if (XMODE == 0) {
        int m_l = tid & 63;
        int mg = bm + m_l;
        xb = mg / 121;
        xp = mg % 121;
    }

    for (int k0 = 0; k0 < Kd; k0 += 16) {
        __syncthreads();
        if (XMODE == 0) {
            int m_l = tid & 63;
            const float* xbase = X + ((size_t)xb * Kd) * 121 + xp;
            #pragma unroll
            for (int t = 0; t < 4; ++t) {
                int k_l = (tid >> 6) + 4 * t;
                Xs[k_l][m_l] = xbase[(size_t)(k0 + k_l) * 121];
            }
        } else {
            int k_l = tid & 15;
            int m_l0 = tid >> 4;
            #pragma unroll
            for (int t = 0; t < 4; ++t) {
                int m_l = m_l0 + 16 * t;
                Xs[k_l][m_l] = X[(size_t)(bm + m_l) * Kd + k0 + k_l];
            }
        }
        {
            int k_l = tid & 15;
            int n_l0 = tid >> 4;
            #pragma unroll
            for (int t = 0; t < 4; ++t) {
                int n_l = n_l0 + 16 * t;
                Ws[k_l][n_l] = W[(size_t)(bn + n_l) * Kd + k0 + k_l];
            }
        }
        __syncthreads();
        #pragma unroll
        for (int k = 0; k < 16; ++k) {
            float a0 = Xs[k][tm + 0], a1 = Xs[k][tm + 1], a2 = Xs[k][tm + 2], a3 = Xs[k][tm + 3];
            float w0 = Ws[k][tn + 0], w1 = Ws[k][tn + 1], w2 = Ws[k][tn + 2], w3 = Ws[k][tn + 3];
            acc[0][0] += a0 * w0; acc[0][1] += a0 * w1; acc[0][2] += a0 * w2; acc[0][3] += a0 * w3;
            acc[1][0] += a1 * w0; acc[1][1] += a1 * w1; acc[1][2] += a1 * w2; acc[1][3] += a1 * w3;
            acc[2][0] += a2 * w0; acc[2][1] += a2 * w1; acc[2][2] += a2 * w2; acc[2][3] += a2 * w3;
            acc[3][0] += a3 * w0; acc[3][1] += a3 * w1; acc[3][2] += a3 * w2; acc[3][3] += a3 * w3;
        }
    }

    const float inv_sqrt = 1.0f / sqrtf(1.0f + BNEPS);
    #pragma unroll
    for (int j = 0; j < 4; ++j) {
        int n = bn + tn + j;
        float sc = g[n] * inv_sqrt;
        float bo = bias[n];
        float bbn = bb[n];
        #pragma unroll
        for (int i = 0; i < 4; ++i) {
            int m = bm + tm + i;
            float v = (acc[i][j] + bo) * sc + bbn;
            v = fmaxf(v, 0.0f);
            if (ATOM) {
                atomicAdd(&Y[(size_t)(m % 121) * N + n], v);
            } else {
                Y[(size_t)m * N + n] = v;
            }
        }
    }
}

// asum[p*1024+o] = sum_b Y2[(b*121+p)*1024+o]
__global__ void batch_sum_kernel(const float* __restrict__ Y2, float* __restrict__ asum)
{
    int idx = blockIdx.x * blockDim.x + threadIdx.x;
    if (idx >= SS * 1024) return;
    int p = idx / 1024, o = idx % 1024;
    const float* src = Y2 + (size_t)p * 1024 + o;
    float s = 0.f;
    for (int b = 0; b < BDIM_B; ++b) s += src[(size_t)b * SS * 1024];
    asum[idx] = s;
}

__global__ void zero_kernel(float* __restrict__ p, int n)
{
    int i = blockIdx.x * blockDim.x + threadIdx.x;
    if (i < n) p[i] = 0.f;
}

// out = act(bn(A[p,:] . W[n,:] + bias[n]))  P=121 rows
// act 0: relu, 1: sigmoid.  outMode 0: out[p*N+n], 1: out[n*121+p]
__global__ void small_fc_kernel(const float* __restrict__ A, const float* __restrict__ W,
                                const float* __restrict__ bias, const float* __restrict__ g,
                                const float* __restrict__ bb, float* __restrict__ out,
                                int N, int Kd, int act, int outMode)
{
    int p = blockIdx.x;
    int n = blockIdx.y * blockDim.x + threadIdx.x;
    if (n >= N) return;
    const float* a = A + (size_t)p * Kd;
    const float* w = W + (size_t)n * Kd;
    float s = 0.f;
    for (int k = 0; k < Kd; k += 4) {
        s += a[k] * w[k] + a[k + 1] * w[k + 1] + a[k + 2] * w[k + 2] + a[k + 3] * w[k + 3];
    }
    s = (s + bias[n]) * (g[n] * (1.0f / sqrtf(1.0f + BNEPS))) + bb[n];
    s = (act == 0) ? fmaxf(s, 0.f) : 1.f / (1.f + expf(-s));
    if (outMode == 0) out[(size_t)p * N + n] = s;
    else out[(size_t)n * SS + p] = s;
}

// y[b*512+c] = sum_p X[b,c,p] * dct[c,p]
__global__ void dct_pool_kernel(const float* __restrict__ X, const float* __restrict__ dct,
                                float* __restrict__ y, int Bn)
{
    int idx = blockIdx.x * blockDim.x + threadIdx.x;
    if (idx >= Bn * CDIM) return;
    int c = idx % CDIM;
    const float* xp = X + (size_t)idx * SS;
    const float* dp = dct + (size_t)c * SS;
    float s = 0.f;
    for (int p = 0; p < SS; ++p) s += xp[p] * dp[p];
    y[idx] = s;
}

// y2[b*32+o] = relu(y[b,:] . fc1[o,:])
__global__ void fc1_kernel(const float* __restrict__ y, const float* __restrict__ fc1,
                           float* __restrict__ y2, int Bn)
{
    int idx = blockIdx.x * blockDim.x + threadIdx.x;
    if (idx >= Bn * 32) return;
    int b = idx / 32, o = idx % 32;
    const float* yb = y + (size_t)b * CDIM;
    const float* w = fc1 + (size_t)o * CDIM;
    float s = 0.f;
    for (int k = 0; k < CDIM; ++k) s += yb[k] * w[k];
    y2[idx] = fmaxf(s, 0.f);
}

// ck[b*4608+o] = sigmoid(y2[b,:] . fc2[o,:]) * bn_ch(c=o/9)
__global__ void fc2_ck_kernel(const float* __restrict__ y2, const float* __restrict__ fc2,
                              const float* __restrict__ g_ch, const float* __restrict__ b_ch,
                              float* __restrict__ ck, int Bn)
{
    int idx = blockIdx.x * blockDim.x + threadIdx.x;
    if (idx >= Bn * CDIM * KK) return;
    int b = idx / (CDIM * KK), o = idx % (CDIM * KK);
    int c = o / KK;
    const float* yb = y2 + (size_t)b * 32;
    const float* w = fc2 + (size_t)o * 32;
    float s = 0.f;
    #pragma unroll
    for (int k = 0; k < 32; ++k) s += yb[k] * w[k];
    s = 1.f / (1.f + expf(-s));
    s = s * (g_ch[c] * (1.0f / sqrtf(1.0f + BNEPS))) + b_ch[c];
    ck[idx] = s;
}

// sk[b*121*9 + p*9 + k9] = bn_sp(p)( x[b,:,p] . w_conv[k9,:] + b_conv[k9] )
__global__ void spatial_k_kernel(const float* __restrict__ X, const float* __restrict__ w_conv,
                                 const float* __restrict__ b_conv, const float* __restrict__ g_sp,
                                 const float* __restrict__ b_sp, float* __restrict__ sk, int Bn)
{
    int idx = blockIdx.x * blockDim.x + threadIdx.x;
    if (idx >= Bn * SS * KK) return;
    int k9 = idx % KK;
    int bp = idx / KK;
    int p = bp % SS, b = bp / SS;
    const float* xp = X + (size_t)b * CDIM * SS + p;
    const float* w = w_conv + (size_t)k9 * CDIM;
    float s = 0.f;
    for (int c = 0; c < CDIM; ++c) s += xp[(size_t)c * SS] * w[c];
    s += b_conv[k9];
    s = s * (g_sp[p] * (1.0f / sqrtf(1.0f + BNEPS))) + b_sp[p];
    sk[idx] = s;
}

// tk[c*1089 + p*9 + k9] = sk_t[p*9+k9] * ck_t[c*9+k9]
__global__ void task_kernel_write(const float* __restrict__ sk_t, const float* __restrict__ ck_t,
                                  float* __restrict__ tk)
{
    int idx = blockIdx.x * blockDim.x + threadIdx.x;
    if (idx >= CDIM * SS * KK) return;
    int k9 = idx % KK;
    int pc = idx / KK;
    int p = pc % SS, c = pc / SS;
    tk[idx] = sk_t[p * KK + k9] * ck_t[c * KK + k9];
}

// out0[b,c,p] = (1/9) sum_k unfold(x)[...,k] * tk[c,p,k] * sk[b,p,k] * ck[b,c,k] + x[b,c,p]
__global__ void final_kernel(const float* __restrict__ x, const float* __restrict__ tk,
                             const float* __restrict__ sk, const float* __restrict__ ck,
                             float* __restrict__ out0)
{
    int idx = blockIdx.x * blockDim.x + threadIdx.x;
    if (idx >= BDIM_B * CDIM * SS) return;
    int p = idx % SS;
    int bc = idx / SS;
    int c = bc % CDIM, b = bc / CDIM;
    int h = p / 11, w = p % 11;
    const float* xp = x + (size_t)bc * SS;
    const float* tkp = tk + ((size_t)c * SS + p) * KK;
    const float* skp = sk + ((size_t)b * SS + p) * KK;
    const float* ckp = ck + ((size_t)b * CDIM + c) * KK;
    float acc = 0.f;
    #pragma unroll
    for (int di = 0; di < 3; ++di) {
        int hh = h + di - 1;
        #pragma unroll
        for (int dj = 0; dj < 3; ++dj) {
            int ww = w + dj - 1;
            int k = di * 3 + dj;
            float xv = (hh >= 0 && hh < 11 && ww >= 0 && ww < 11) ? xp[hh * 11 + ww] : 0.f;
            acc += xv * tkp[k] * skp[k] * ckp[k];
        }
    }
    out0[idx] = acc * (1.0f / 9.0f) + xp[p];
}

extern "C" void kernel_launch(void* const* d_in, const int* in_sizes, int n_in,
                              void* d_out, int out_size, void* d_ws, size_t ws_size,
                              hipStream_t stream)
{
    const float* x      = (const float*)d_in[0];
    const float* dct_w  = (const float*)d_in[1];
    const float* w_conv = (const float*)d_in[2];
    const float* b_conv = (const float*)d_in[3];
    const float* g_sp   = (const float*)d_in[4];
    const float* b_sp   = (const float*)d_in[5];
    const float* g_ch   = (const float*)d_in[6];
    const float* b_ch   = (const float*)d_in[7];
    const float* fc1    = (const float*)d_in[8];
    const float* fc2    = (const float*)d_in[9];
    const float* up_w1  = (const float*)d_in[10];
    const float* up_b1  = (const float*)d_in[11];
    const float* up_g1  = (const float*)d_in[12];
    const float* up_bb1 = (const float*)d_in[13];
    const float* up_w2  = (const float*)d_in[14];
    const float* up_b2  = (const float*)d_in[15];
    const float* up_g2  = (const float*)d_in[16];
    const float* up_bb2 = (const float*)d_in[17];
    const float* lo_w1  = (const float*)d_in[18];
    const float* lo_b1  = (const float*)d_in[19];
    const float* lo_g1  = (const float*)d_in[20];
    const float* lo_bb1 = (const float*)d_in[21];
    const float* lo_w2  = (const float*)d_in[22];
    const float* lo_b2  = (const float*)d_in[23];
    const float* lo_g2  = (const float*)d_in[24];
    const float* lo_bb2 = (const float*)d_in[25];

    float* out0 = (float*)d_out;                       // (B,C,11,11)
    float* tk   = out0 + (size_t)BDIM_B * CDIM * SS;   // (1,C,11,11,3,3)

    // workspace layout
    float* ws = (float*)d_ws;
    size_t off = 0;
    auto alloc = [&](size_t n) { float* p = ws + off; off += (n + 15) & ~(size_t)15; return p; };
    float* Y1     = alloc((size_t)MROWS * 1024);
    float* asum   = alloc(SS * 1024);
    float* a3     = alloc(SS * 1024);
    float* task_s = alloc(CDIM * SS);
    float* ybuf   = alloc(BDIM_B * CDIM);
    float* y2buf  = alloc(BDIM_B * 32);
    float* ckbuf  = alloc((size_t)BDIM_B * CDIM * KK);
    float* skbuf  = alloc((size_t)BDIM_B * SS * KK);
    float* y_t    = alloc(CDIM);
    float* y2_t   = alloc(32);
    float* ck_t   = alloc(CDIM * KK);
    float* sk_t   = alloc(SS * KK);
    size_t base = off;
    float* Y2 = ws + off;
    bool haveY2 = (ws_size >= (base + (size_t)MROWS * 1024) * sizeof(float));

    dim3 gemm_grid(MROWS / 64, 1024 / 64);

    // up path GEMM1: x (conv1x1 view) -> Y1
    hipLaunchKernelGGL((gemm_bn_relu<0, false>), gemm_grid, dim3(256), 0, stream,
                       x, up_w1, up_b1, up_g1, up_bb1, Y1, MROWS, 1024, CDIM);

    if (haveY2) {
        hipLaunchKernelGGL((gemm_bn_relu<1, false>), gemm_grid, dim3(256), 0, stream,
                           Y1, up_w2, up_b2, up_g2, up_bb2, Y2, MROWS, 1024, 1024);
        hipLaunchKernelGGL(batch_sum_kernel, dim3((SS * 1024 + 255) / 256), dim3(256), 0, stream,
                           Y2, asum);
    } else {
        hipLaunchKernelGGL(zero_kernel, dim3((SS * 1024 + 255) / 256), dim3(256), 0, stream,
                           asum, SS * 1024);
        hipLaunchKernelGGL((gemm_bn_relu<1, true>), gemm_grid, dim3(256), 0, stream,
                           Y1, up_w2, up_b2, up_g2, up_bb2, asum, MROWS, 1024, 1024);
    }

    // lo path (121-row tiny GEMMs)
    hipLaunchKernelGGL(small_fc_kernel, dim3(SS, 4), dim3(256), 0, stream,
                       asum, lo_w1, lo_b1, lo_g1, lo_bb1, a3, 1024, 1024, 0, 0);
    hipLaunchKernelGGL(small_fc_kernel, dim3(SS, 2), dim3(256), 0, stream,
                       a3, lo_w2, lo_b2, lo_g2, lo_bb2, task_s, CDIM, 1024, 1, 1);

    // channel kernels (instance batch + task)
    hipLaunchKernelGGL(dct_pool_kernel, dim3((BDIM_B * CDIM + 255) / 256), dim3(256), 0, stream,
                       x, dct_w, ybuf, BDIM_B);
    hipLaunchKernelGGL(dct_pool_kernel, dim3((CDIM + 255) / 256), dim3(256), 0, stream,
                       task_s, dct_w, y_t, 1);
    hipLaunchKernelGGL(fc1_kernel, dim3((BDIM_B * 32 + 255) / 256), dim3(256), 0, stream,
                       ybuf, fc1, y2buf, BDIM_B);
    hipLaunchKernelGGL(fc1_kernel, dim3(1), dim3(256), 0, stream,
                       y_t, fc1, y2_t, 1);
    hipLaunchKernelGGL(fc2_ck_kernel, dim3((BDIM_B * CDIM * KK + 255) / 256), dim3(256), 0, stream,
                       y2buf, fc2, g_ch, b_ch, ckbuf, BDIM_B);
    hipLaunchKernelGGL(fc2_ck_kernel, dim3((CDIM * KK + 255) / 256), dim3(256), 0, stream,
                       y2_t, fc2, g_ch, b_ch, ck_t, 1);

    // spatial kernels
    hipLaunchKernelGGL(spatial_k_kernel, dim3((BDIM_B * SS * KK + 255) / 256), dim3(256), 0, stream,
                       x, w_conv, b_conv, g_sp, b_sp, skbuf, BDIM_B);
    hipLaunchKernelGGL(spatial_k_kernel, dim3((SS * KK + 255) / 256), dim3(256), 0, stream,
                       task_s, w_conv, b_conv, g_sp, b_sp, sk_t, 1);

    // task kernel output
    hipLaunchKernelGGL(task_kernel_write, dim3((CDIM * SS * KK + 255) / 256), dim3(256), 0, stream,
                       sk_t, ck_t, tk);

    // final fused unfold * kernel mean + residual
    hipLaunchKernelGGL(final_kernel, dim3((BDIM_B * CDIM * SS + 255) / 256), dim3(256), 0, stream,
                       x, tk, skbuf, ckbuf, out0);
}

// Round 2
// 705.685 us; speedup vs baseline: 2.3182x; 2.3182x over previous
//
#include <hip/hip_runtime.h>
#include <hip/hip_bf16.h>
#include <math.h>

#define BNEPS 1e-5f
#define BDIM_B 128
#define CDIM 512
#define SS 121
#define KK 9
#define MROWS (BDIM_B * SS)   // 15488

typedef unsigned short u16;
typedef __bf16 bf16x8 __attribute__((ext_vector_type(8)));
typedef float f32x4 __attribute__((ext_vector_type(4)));

__device__ __forceinline__ u16 f2bf(float f) {
    union { float f; unsigned int u; } v; v.f = f;
    unsigned int r = v.u + 0x7FFF + ((v.u >> 16) & 1);   // RNE
    return (u16)(r >> 16);
}

__device__ __forceinline__ void gld16(const u16* g, u16* l) {
    __builtin_amdgcn_global_load_lds(
        (const __attribute__((address_space(1))) void*)g,
        (__attribute__((address_space(3))) void*)l, 16, 0, 0);
}

// ---------------------------------------------------------------------------
// bf16 MFMA GEMM, 128x128 tile, BK=32, 256 threads (4 waves, 2x2 wave grid).
// A: (M,Kd) bf16 row-major.  Bw: (N,Kd) bf16 row-major (B^T form).
// epilogue: v = relu((acc + bias[n]) * g[n]/sqrt(1+eps) + bb[n])
// MODE 1: store bf16 to Yout[(m%121)*128 + m/121][n]   (p-major remap)
// MODE 2: block rows are all one p (p = blockIdx.x); reduce v over the 128
//         rows and store fp32 asum[p*1024 + n]  (fused relu->batch-sum)
// ---------------------------------------------------------------------------
template<int MODE>
__global__ __launch_bounds__(256)
void gemm_mfma(const u16* __restrict__ A, const u16* __restrict__ Bw,
               const float* __restrict__ bias, const float* __restrict__ g,
               const float* __restrict__ bb, void* __restrict__ out, int Kd)
{
    __shared__ __align__(16) u16 Als[128 * 32];
    __shared__ __align__(16) u16 Bls[128 * 32];

    const int tid  = threadIdx.x;
    const int lane = tid & 63;
    const int w    = tid >> 6;
    const int wm   = w >> 1, wn = w & 1;
    const int bm   = blockIdx.x * 128;
    const int bn   = blockIdx.y * 128;

    f32x4 acc[4][4] = {};

    // staging addressing: thread t loads 16B; 4 threads per 32-elem k-row
    const int subrow = tid >> 2;         // 0..63
    const int kq     = tid & 3;          // 16B chunk within k-row
    const u16* Ab = A  + (size_t)(bm + subrow) * Kd + kq * 8;
    const u16* Bb = Bw + (size_t)(bn + subrow) * Kd + kq * 8;
    // wave-uniform LDS bases (lane i lands at base + i*16B)
    u16* Al0 = &Als[(w * 16) * 32];
    u16* Al1 = &Als[(w * 16 + 64) * 32];
    u16* Bl0 = &Bls[(w * 16) * 32];
    u16* Bl1 = &Bls[(w * 16 + 64) * 32];

    const int fa_row = wm * 64 + (lane & 15);
    const int fb_row = wn * 64 + (lane & 15);
    const int kofs   = (lane >> 4) * 8;

    for (int k0 = 0; k0 < Kd; k0 += 32) {
        __syncthreads();
        gld16(Ab + k0, Al0);
        gld16(Ab + (size_t)64 * Kd + k0, Al1);
        gld16(Bb + k0, Bl0);
        gld16(Bb + (size_t)64 * Kd + k0, Bl1);
        __syncthreads();

        bf16x8 af[4], bfv[4];
        #pragma unroll
        for (int i = 0; i < 4; ++i)
            af[i] = *(bf16x8*)&Als[(fa_row + i * 16) * 32 + kofs];
        #pragma unroll
        for (int j = 0; j < 4; ++j)
            bfv[j] = *(bf16x8*)&Bls[(fb_row + j * 16) * 32 + kofs];
        #pragma unroll
        for (int i = 0; i < 4; ++i)
            #pragma unroll
            for (int j = 0; j < 4; ++j)
                acc[i][j] = __builtin_amdgcn_mfma_f32_16x16x32_bf16(af[i], bfv[j], acc[i][j], 0, 0, 0);
    }

    const float inv = 1.0f / sqrtf(1.0f + BNEPS);

    if (MODE == 1) {
        u16* Y = (u16*)out;
        // precompute p-major destination rows for this lane's 16 m's
        int dstrow[4][4];
        #pragma unroll
        for (int i = 0; i < 4; ++i) {
            int mb = bm + wm * 64 + i * 16 + (lane >> 4) * 4;
            #pragma unroll
            for (int r = 0; r < 4; ++r) {
                int m = mb + r;
                int b = m / 121, p = m - b * 121;
                dstrow[i][r] = p * 128 + b;
            }
        }
        #pragma unroll
        for (int j = 0; j < 4; ++j) {
            int n = bn + wn * 64 + j * 16 + (lane & 15);
            float sc = g[n] * inv, bo = bias[n], bv = bb[n];
            #pragma unroll
            for (int i = 0; i < 4; ++i)
                #pragma unroll
                for (int r = 0; r < 4; ++r) {
                    float v = (acc[i][j][r] + bo) * sc + bv;
                    v = fmaxf(v, 0.0f);
                    Y[(size_t)dstrow[i][r] * 1024 + n] = f2bf(v);
                }
        }
    } else {
        // MODE 2: all 128 rows of this block are pixel p = blockIdx.x
        float ps[4];
        #pragma unroll
        for (int j = 0; j < 4; ++j) {
            int n = bn + wn * 64 + j * 16 + (lane & 15);
            float sc = g[n] * inv, bo = bias[n], bv = bb[n];
            float s = 0.f;
            #pragma unroll
            for (int i = 0; i < 4; ++i)
                #pragma unroll
                for (int r = 0; r < 4; ++r) {
                    float v = (acc[i][j][r] + bo) * sc + bv;
                    s += fmaxf(v, 0.0f);
                }
            ps[j] = s;
        }
        __syncthreads();                       // all frag reads done; reuse LDS
        float* red = (float*)Als;              // 8 x 128 fp32 = 4KB
        #pragma unroll
        for (int j = 0; j < 4; ++j)
            red[(wm * 4 + (lane >> 4)) * 128 + wn * 64 + j * 16 + (lane & 15)] = ps[j];
        __syncthreads();
        if (tid < 128) {
            float s = 0.f;
            #pragma unroll
            for (int r = 0; r < 8; ++r) s += red[r * 128 + tid];
            ((float*)out)[(size_t)blockIdx.x * 1024 + bn + tid] = s;
        }
    }
}

// x (B,C,11,11) fp32 -> Xb[(b*121+p)*512 + c] bf16  (LDS tile transpose)
__global__ void transpose_x(const float* __restrict__ x, u16* __restrict__ Xb)
{
    __shared__ float t[64 * 121];
    int b = blockIdx.x, c0 = blockIdx.y * 64;
    for (int idx = threadIdx.x; idx < 64 * 121; idx += 256) {
        int c = idx / 121, p = idx - c * 121;
        t[idx] = x[((size_t)b * 512 + c0 + c) * 121 + p];
    }
    __syncthreads();
    for (int idx = threadIdx.x; idx < 121 * 64; idx += 256) {
        int p = idx >> 6, c = idx & 63;
        Xb[((size_t)(b * 121 + p)) * 512 + c0 + c] = f2bf(t[c * 121 + p]);
    }
}

__global__ void f32_to_bf16(const float* __restrict__ in, u16* __restrict__ out, int n)
{
    int i = blockIdx.x * 256 + threadIdx.x;
    if (i < n) out[i] = f2bf(in[i]);
}

// out = act(bn(A[p,:] . W[n,:] + bias[n]))  P=121 rows
__global__ void small_fc_kernel(const float* __restrict__ A, const float* __restrict__ W,
                                const float* __restrict__ bias, const float* __restrict__ g,
                                const float* __restrict__ bb, float* __restrict__ out,
                                int N, int Kd, int act, int outMode)
{
    int p = blockIdx.x;
    int n = blockIdx.y * blockDim.x + threadIdx.x;
    if (n >= N) return;
    const float* a = A + (size_t)p * Kd;
    const float* w = W + (size_t)n * Kd;
    float s = 0.f;
    for (int k = 0; k < Kd; k += 4) {
        s += a[k] * w[k] + a[k + 1] * w[k + 1] + a[k + 2] * w[k + 2] + a[k + 3] * w[k + 3];
    }
    s = (s + bias[n]) * (g[n] * (1.0f / sqrtf(1.0f + BNEPS))) + bb[n];
    s = (act == 0) ? fmaxf(s, 0.f) : 1.f / (1.f + expf(-s));
    if (outMode == 0) out[(size_t)p * N + n] = s;
    else out[(size_t)n * SS + p] = s;
}

// y[b*512+c] = sum_p X[b,c,p] * dct[c,p]
__global__ void dct_pool_kernel(const float* __restrict__ X, const float* __restrict__ dct,
                                float* __restrict__ y, int Bn)
{
    int idx = blockIdx.x * blockDim.x + threadIdx.x;
    if (idx >= Bn * CDIM) return;
    int c = idx % CDIM;
    const float* xp = X + (size_t)idx * SS;
    const float* dp = dct + (size_t)c * SS;
    float s = 0.f;
    for (int p = 0; p < SS; ++p) s += xp[p] * dp[p];
    y[idx] = s;
}

// y2[b*32+o] = relu(y[b,:] . fc1[o,:])
__global__ void fc1_kernel(const float* __restrict__ y, const float* __restrict__ fc1,
                           float* __restrict__ y2, int Bn)
{
    int idx = blockIdx.x * blockDim.x + threadIdx.x;
    if (idx >= Bn * 32) return;
    int b = idx / 32, o = idx % 32;
    const float* yb = y + (size_t)b * CDIM;
    const float* w = fc1 + (size_t)o * CDIM;
    float s = 0.f;
    for (int k = 0; k < CDIM; ++k) s += yb[k] * w[k];
    y2[idx] = fmaxf(s, 0.f);
}

// ck[b*4608+o] = (sigmoid(y2[b,:] . fc2[o,:])) * bn_ch(c=o/9)
__global__ void fc2_ck_kernel(const float* __restrict__ y2, const float* __restrict__ fc2,
                              const float* __restrict__ g_ch, const float* __restrict__ b_ch,
                              float* __restrict__ ck, int Bn)
{
    int idx = blockIdx.x * blockDim.x + threadIdx.x;
    if (idx >= Bn * CDIM * KK) return;
    int b = idx / (CDIM * KK), o = idx % (CDIM * KK);
    int c = o / KK;
    const float* yb = y2 + (size_t)b * 32;
    const float* w = fc2 + (size_t)o * 32;
    float s = 0.f;
    #pragma unroll
    for (int k = 0; k < 32; ++k) s += yb[k] * w[k];
    s = 1.f / (1.f + expf(-s));
    s = s * (g_ch[c] * (1.0f / sqrtf(1.0f + BNEPS))) + b_ch[c];
    ck[idx] = s;
}

// sk[b*121*9 + p*9 + k9] = bn_sp(p)( x[b,:,p] . w_conv[k9,:] + b_conv[k9] )
__global__ void spatial_k_kernel(const float* __restrict__ X, const float* __restrict__ w_conv,
                                 const float* __restrict__ b_conv, const float* __restrict__ g_sp,
                                 const float* __restrict__ b_sp, float* __restrict__ sk, int Bn)
{
    int idx = blockIdx.x * blockDim.x + threadIdx.x;
    if (idx >= Bn * SS * KK) return;
    int k9 = idx % KK;
    int bp = idx / KK;
    int p = bp % SS, b = bp / SS;
    const float* xp = X + (size_t)b * CDIM * SS + p;
    const float* w = w_conv + (size_t)k9 * CDIM;
    float s = 0.f;
    for (int c = 0; c < CDIM; ++c) s += xp[(size_t)c * SS] * w[c];
    s += b_conv[k9];
    s = s * (g_sp[p] * (1.0f / sqrtf(1.0f + BNEPS))) + b_sp[p];
    sk[idx] = s;
}

// tk[c*1089 + p*9 + k9] = sk_t[p*9+k9] * ck_t[c*9+k9]
__global__ void task_kernel_write(const float* __restrict__ sk_t, const float* __restrict__ ck_t,
                                  float* __restrict__ tk)
{
    int idx = blockIdx.x * blockDim.x + threadIdx.x;
    if (idx >= CDIM * SS * KK) return;
    int k9 = idx % KK;
    int pc = idx / KK;
    int p = pc % SS, c = pc / SS;
    tk[idx] = sk_t[p * KK + k9] * ck_t[c * KK + k9];
}

// out0[b,c,p] = (1/9) sum_k unfold(x)[...,k] * tk[c,p,k] * sk[b,p,k] * ck[b,c,k] + x[b,c,p]
__global__ void final_kernel(const float* __restrict__ x, const float* __restrict__ tk,
                             const float* __restrict__ sk, const float* __restrict__ ck,
                             float* __restrict__ out0)
{
    int idx = blockIdx.x * blockDim.x + threadIdx.x;
    if (idx >= BDIM_B * CDIM * SS) return;
    int p = idx % SS;
    int bc = idx / SS;
    int c = bc % CDIM, b = bc / CDIM;
    int h = p / 11, w = p % 11;
    const float* xp = x + (size_t)bc * SS;
    const float* tkp = tk + ((size_t)c * SS + p) * KK;
    const float* skp = sk + ((size_t)b * SS + p) * KK;
    const float* ckp = ck + ((size_t)b * CDIM + c) * KK;
    float acc = 0.f;
    #pragma unroll
    for (int di = 0; di < 3; ++di) {
        int hh = h + di - 1;
        #pragma unroll
        for (int dj = 0; dj < 3; ++dj) {
            int ww = w + dj - 1;
            int k = di * 3 + dj;
            float xv = (hh >= 0 && hh < 11 && ww >= 0 && ww < 11) ? xp[hh * 11 + ww] : 0.f;
            acc += xv * tkp[k] * skp[k] * ckp[k];
        }
    }
    out0[idx] = acc * (1.0f / 9.0f) + xp[p];
}

extern "C" void kernel_launch(void* const* d_in, const int* in_sizes, int n_in,
                              void* d_out, int out_size, void* d_ws, size_t ws_size,
                              hipStream_t stream)
{
    const float* x      = (const float*)d_in[0];
    const float* dct_w  = (const float*)d_in[1];
    const float* w_conv = (const float*)d_in[2];
    const float* b_conv = (const float*)d_in[3];
    const float* g_sp   = (const float*)d_in[4];
    const float* b_sp   = (const float*)d_in[5];
    const float* g_ch   = (const float*)d_in[6];
    const float* b_ch   = (const float*)d_in[7];
    const float* fc1    = (const float*)d_in[8];
    const float* fc2    = (const float*)d_in[9];
    const float* up_w1  = (const float*)d_in[10];
    const float* up_b1  = (const float*)d_in[11];
    const float* up_g1  = (const float*)d_in[12];
    const float* up_bb1 = (const float*)d_in[13];
    const float* up_w2  = (const float*)d_in[14];
    const float* up_b2  = (const float*)d_in[15];
    const float* up_g2  = (const float*)d_in[16];
    const float* up_bb2 = (const float*)d_in[17];
    const float* lo_w1  = (const float*)d_in[18];
    const float* lo_b1  = (const float*)d_in[19];
    const float* lo_g1  = (const float*)d_in[20];
    const float* lo_bb1 = (const float*)d_in[21];
    const float* lo_w2  = (const float*)d_in[22];
    const float* lo_b2  = (const float*)d_in[23];
    const float* lo_g2  = (const float*)d_in[24];
    const float* lo_bb2 = (const float*)d_in[25];

    float* out0 = (float*)d_out;                       // (B,C,11,11)
    float* tk   = out0 + (size_t)BDIM_B * CDIM * SS;   // (1,C,11,11,3,3)

    // workspace layout (bytes, 64B-aligned chunks)
    char* ws = (char*)d_ws;
    size_t off = 0;
    auto alloc = [&](size_t bytes) { void* p = ws + off; off += (bytes + 63) & ~(size_t)63; return p; };
    u16*   Xb     = (u16*)alloc((size_t)MROWS * 512 * 2);
    u16*   Y1     = (u16*)alloc((size_t)MROWS * 1024 * 2);
    u16*   w1b    = (u16*)alloc((size_t)1024 * 512 * 2);
    u16*   w2b    = (u16*)alloc((size_t)1024 * 1024 * 2);
    float* asum   = (float*)alloc((size_t)SS * 1024 * 4);
    float* a3     = (float*)alloc((size_t)SS * 1024 * 4);
    float* task_s = (float*)alloc((size_t)CDIM * SS * 4);
    float* ybuf   = (float*)alloc((size_t)BDIM_B * CDIM * 4);
    float* y2buf  = (float*)alloc((size_t)BDIM_B * 32 * 4);
    float* ckbuf  = (float*)alloc((size_t)BDIM_B * CDIM * KK * 4);
    float* skbuf  = (float*)alloc((size_t)BDIM_B * SS * KK * 4);
    float* y_t    = (float*)alloc((size_t)CDIM * 4);
    float* y2_t   = (float*)alloc((size_t)32 * 4);
    float* ck_t   = (float*)alloc((size_t)CDIM * KK * 4);
    float* sk_t   = (float*)alloc((size_t)SS * KK * 4);

    // --- prep: bf16 conversions ---
    hipLaunchKernelGGL(transpose_x, dim3(BDIM_B, 8), dim3(256), 0, stream, x, Xb);
    hipLaunchKernelGGL(f32_to_bf16, dim3((1024 * 512 + 255) / 256), dim3(256), 0, stream,
                       up_w1, w1b, 1024 * 512);
    hipLaunchKernelGGL(f32_to_bf16, dim3((1024 * 1024 + 255) / 256), dim3(256), 0, stream,
                       up_w2, w2b, 1024 * 1024);

    // --- up path: two MFMA GEMMs; batch-sum fused into GEMM2 epilogue ---
    dim3 ggrid(MROWS / 128, 1024 / 128);   // (121, 8)
    hipLaunchKernelGGL((gemm_mfma<1>), ggrid, dim3(256), 0, stream,
                       Xb, w1b, up_b1, up_g1, up_bb1, (void*)Y1, 512);
    hipLaunchKernelGGL((gemm_mfma<2>), ggrid, dim3(256), 0, stream,
                       Y1, w2b, up_b2, up_g2, up_bb2, (void*)asum, 1024);

    // --- lo path (121-row tiny GEMMs) ---
    hipLaunchKernelGGL(small_fc_kernel, dim3(SS, 4), dim3(256), 0, stream,
                       asum, lo_w1, lo_b1, lo_g1, lo_bb1, a3, 1024, 1024, 0, 0);
    hipLaunchKernelGGL(small_fc_kernel, dim3(SS, 2), dim3(256), 0, stream,
                       a3, lo_w2, lo_b2, lo_g2, lo_bb2, task_s, CDIM, 1024, 1, 1);

    // --- channel kernels (instance batch + task) ---
    hipLaunchKernelGGL(dct_pool_kernel, dim3((BDIM_B * CDIM + 255) / 256), dim3(256), 0, stream,
                       x, dct_w, ybuf, BDIM_B);
    hipLaunchKernelGGL(dct_pool_kernel, dim3((CDIM + 255) / 256), dim3(256), 0, stream,
                       task_s, dct_w, y_t, 1);
    hipLaunchKernelGGL(fc1_kernel, dim3((BDIM_B * 32 + 255) / 256), dim3(256), 0, stream,
                       ybuf, fc1, y2buf, BDIM_B);
    hipLaunchKernelGGL(fc1_kernel, dim3(1), dim3(256), 0, stream,
                       y_t, fc1, y2_t, 1);
    hipLaunchKernelGGL(fc2_ck_kernel, dim3((BDIM_B * CDIM * KK + 255) / 256), dim3(256), 0, stream,
                       y2buf, fc2, g_ch, b_ch, ckbuf, BDIM_B);
    hipLaunchKernelGGL(fc2_ck_kernel, dim3((CDIM * KK + 255) / 256), dim3(256), 0, stream,
                       y2_t, fc2, g_ch, b_ch, ck_t, 1);

    // --- spatial kernels ---
    hipLaunchKernelGGL(spatial_k_kernel, dim3((BDIM_B * SS * KK + 255) / 256), dim3(256), 0, stream,
                       x, w_conv, b_conv, g_sp, b_sp, skbuf, BDIM_B);
    hipLaunchKernelGGL(spatial_k_kernel, dim3((SS * KK + 255) / 256), dim3(256), 0, stream,
                       task_s, w_conv, b_conv, g_sp, b_sp, sk_t, 1);

    // --- task kernel output ---
    hipLaunchKernelGGL(task_kernel_write, dim3((CDIM * SS * KK + 255) / 256), dim3(256), 0, stream,
                       sk_t, ck_t, tk);

    // --- final fused unfold * kernel mean + residual ---
    hipLaunchKernelGGL(final_kernel, dim3((BDIM_B * CDIM * SS + 255) / 256), dim3(256), 0, stream,
                       x, tk, skbuf, ckbuf, out0);
}

// Round 3
// 446.236 us; speedup vs baseline: 3.6660x; 1.5814x over previous
//
#include <hip/hip_runtime.h>
#include <hip/hip_bf16.h>
#include <math.h>

#define BNEPS 1e-5f
#define BDIM_B 128
#define CDIM 512
#define SS 121
#define KK 9
#define MROWS (BDIM_B * SS)   // 15488

typedef unsigned short u16;
typedef __bf16 bf16x8 __attribute__((ext_vector_type(8)));
typedef float f32x4 __attribute__((ext_vector_type(4)));

__device__ __forceinline__ u16 f2bf(float f) {
    union { float f; unsigned int u; } v; v.f = f;
    unsigned int r = v.u + 0x7FFF + ((v.u >> 16) & 1);   // RNE
    return (u16)(r >> 16);
}
__device__ __forceinline__ float bf2f(u16 v) {
    union { unsigned int u; float f; } x; x.u = ((unsigned int)v) << 16; return x.f;
}

__device__ __forceinline__ void gld16(const u16* g, u16* l) {
    __builtin_amdgcn_global_load_lds(
        (const __attribute__((address_space(1))) void*)g,
        (__attribute__((address_space(3))) void*)l, 16, 0, 0);
}

// ---------------------------------------------------------------------------
// bf16 MFMA GEMM, 128x128 tile, BK=32, 256 threads (4 waves, 2x2 wave grid).
// A: (M,Kd) bf16 row-major.  Bw: (N,Kd) bf16 row-major (B^T form).
// epilogue: v = relu((acc + bias[n]) * g[n]/sqrt(1+eps) + bb[n])
// MODE 1: store bf16 to Yout[(m%121)*128 + m/121][n]   (p-major remap)
// MODE 2: block rows are all one p (p = blockIdx.x); reduce v over the 128
//         rows and store fp32 asum[p*1024 + n]  (fused relu->batch-sum)
// ---------------------------------------------------------------------------
template<int MODE>
__global__ __launch_bounds__(256)
void gemm_mfma(const u16* __restrict__ A, const u16* __restrict__ Bw,
               const float* __restrict__ bias, const float* __restrict__ g,
               const float* __restrict__ bb, void* __restrict__ out, int Kd)
{
    __shared__ __align__(16) u16 Als[128 * 32];
    __shared__ __align__(16) u16 Bls[128 * 32];

    const int tid  = threadIdx.x;
    const int lane = tid & 63;
    const int w    = tid >> 6;
    const int wm   = w >> 1, wn = w & 1;
    const int bm   = blockIdx.x * 128;
    const int bn   = blockIdx.y * 128;

    f32x4 acc[4][4] = {};

    const int subrow = tid >> 2;         // 0..63
    const int kq     = tid & 3;          // 16B chunk within k-row
    const u16* Ab = A  + (size_t)(bm + subrow) * Kd + kq * 8;
    const u16* Bb = Bw + (size_t)(bn + subrow) * Kd + kq * 8;
    u16* Al0 = &Als[(w * 16) * 32];
    u16* Al1 = &Als[(w * 16 + 64) * 32];
    u16* Bl0 = &Bls[(w * 16) * 32];
    u16* Bl1 = &Bls[(w * 16 + 64) * 32];

    const int fa_row = wm * 64 + (lane & 15);
    const int fb_row = wn * 64 + (lane & 15);
    const int kofs   = (lane >> 4) * 8;

    for (int k0 = 0; k0 < Kd; k0 += 32) {
        __syncthreads();
        gld16(Ab + k0, Al0);
        gld16(Ab + (size_t)64 * Kd + k0, Al1);
        gld16(Bb + k0, Bl0);
        gld16(Bb + (size_t)64 * Kd + k0, Bl1);
        __syncthreads();

        bf16x8 af[4], bfv[4];
        #pragma unroll
        for (int i = 0; i < 4; ++i)
            af[i] = *(bf16x8*)&Als[(fa_row + i * 16) * 32 + kofs];
        #pragma unroll
        for (int j = 0; j < 4; ++j)
            bfv[j] = *(bf16x8*)&Bls[(fb_row + j * 16) * 32 + kofs];
        #pragma unroll
        for (int i = 0; i < 4; ++i)
            #pragma unroll
            for (int j = 0; j < 4; ++j)
                acc[i][j] = __builtin_amdgcn_mfma_f32_16x16x32_bf16(af[i], bfv[j], acc[i][j], 0, 0, 0);
    }

    const float inv = 1.0f / sqrtf(1.0f + BNEPS);

    if (MODE == 1) {
        u16* Y = (u16*)out;
        int dstrow[4][4];
        #pragma unroll
        for (int i = 0; i < 4; ++i) {
            int mb = bm + wm * 64 + i * 16 + (lane >> 4) * 4;
            #pragma unroll
            for (int r = 0; r < 4; ++r) {
                int m = mb + r;
                int b = m / 121, p = m - b * 121;
                dstrow[i][r] = p * 128 + b;
            }
        }
        #pragma unroll
        for (int j = 0; j < 4; ++j) {
            int n = bn + wn * 64 + j * 16 + (lane & 15);
            float sc = g[n] * inv, bo = bias[n], bv = bb[n];
            #pragma unroll
            for (int i = 0; i < 4; ++i)
                #pragma unroll
                for (int r = 0; r < 4; ++r) {
                    float v = (acc[i][j][r] + bo) * sc + bv;
                    v = fmaxf(v, 0.0f);
                    Y[(size_t)dstrow[i][r] * 1024 + n] = f2bf(v);
                }
        }
    } else {
        float ps[4];
        #pragma unroll
        for (int j = 0; j < 4; ++j) {
            int n = bn + wn * 64 + j * 16 + (lane & 15);
            float sc = g[n] * inv, bo = bias[n], bv = bb[n];
            float s = 0.f;
            #pragma unroll
            for (int i = 0; i < 4; ++i)
                #pragma unroll
                for (int r = 0; r < 4; ++r) {
                    float v = (acc[i][j][r] + bo) * sc + bv;
                    s += fmaxf(v, 0.0f);
                }
            ps[j] = s;
        }
        __syncthreads();
        float* red = (float*)Als;
        #pragma unroll
        for (int j = 0; j < 4; ++j)
            red[(wm * 4 + (lane >> 4)) * 128 + wn * 64 + j * 16 + (lane & 15)] = ps[j];
        __syncthreads();
        if (tid < 128) {
            float s = 0.f;
            #pragma unroll
            for (int r = 0; r < 8; ++r) s += red[r * 128 + tid];
            ((float*)out)[(size_t)blockIdx.x * 1024 + bn + tid] = s;
        }
    }
}

// x (B,C,11,11) fp32 -> Xb[(b*121+p)*512 + c] bf16  (LDS tile transpose)
__global__ void transpose_x(const float* __restrict__ x, u16* __restrict__ Xb)
{
    __shared__ float t[64 * 121];
    int b = blockIdx.x, c0 = blockIdx.y * 64;
    for (int idx = threadIdx.x; idx < 64 * 121; idx += 256) {
        int c = idx / 121, p = idx - c * 121;
        t[idx] = x[((size_t)b * 512 + c0 + c) * 121 + p];
    }
    __syncthreads();
    for (int idx = threadIdx.x; idx < 121 * 64; idx += 256) {
        int p = idx >> 6, c = idx & 63;
        Xb[((size_t)(b * 121 + p)) * 512 + c0 + c] = f2bf(t[c * 121 + p]);
    }
}

__global__ void f32_to_bf16(const float* __restrict__ in, u16* __restrict__ out, int n)
{
    int i = blockIdx.x * 256 + threadIdx.x;
    if (i < n) out[i] = f2bf(in[i]);
}

// dctT[p*512+c] = dct[c*121+p]
__global__ void transpose_dct(const float* __restrict__ dct, float* __restrict__ dctT)
{
    int idx = blockIdx.x * 256 + threadIdx.x;
    if (idx >= 512 * 121) return;
    int p = idx >> 9, c = idx & 511;
    dctT[idx] = dct[(size_t)c * 121 + p];
}

// ---------------------------------------------------------------------------
// lo-path FC: block = 256 threads computes 64 outputs of row p (4-way k-split).
// grid (121, N/64). A row (Kd<=1024 fp32) staged in LDS.
// ACT 0: relu -> fp32 out[p*N+n]; ACT 1: sigmoid -> bf16 out[p*512+n] (p,c)
// ---------------------------------------------------------------------------
template<int ACT>
__global__ __launch_bounds__(256)
void fc_ksplit(const float* __restrict__ A, const float* __restrict__ W,
               const float* __restrict__ bias, const float* __restrict__ g,
               const float* __restrict__ bb, void* __restrict__ out,
               int N, int Kd)
{
    __shared__ float Als[1024];
    int p = blockIdx.x;
    const float* a = A + (size_t)p * Kd;
    for (int i = threadIdx.x; i < Kd / 4; i += 256)
        ((float4*)Als)[i] = ((const float4*)a)[i];
    __syncthreads();
    int n = blockIdx.y * 64 + (threadIdx.x >> 2);
    int kp = threadIdx.x & 3;
    const float* w = W + (size_t)n * Kd;
    float s0 = 0.f, s1 = 0.f;
    for (int k = kp * 4; k < Kd; k += 32) {
        float4 wv = *(const float4*)(w + k);
        float4 av = *(const float4*)(Als + k);
        s0 += wv.x * av.x + wv.y * av.y + wv.z * av.z + wv.w * av.w;
        float4 wv2 = *(const float4*)(w + k + 16);
        float4 av2 = *(const float4*)(Als + k + 16);
        s1 += wv2.x * av2.x + wv2.y * av2.y + wv2.z * av2.z + wv2.w * av2.w;
    }
    float s = s0 + s1;
    s += __shfl_xor(s, 1);
    s += __shfl_xor(s, 2);
    if (kp == 0) {
        s = (s + bias[n]) * (g[n] * (1.0f / sqrtf(1.0f + BNEPS))) + bb[n];
        if (ACT == 0) {
            ((float*)out)[(size_t)p * N + n] = fmaxf(s, 0.f);
        } else {
            s = 1.f / (1.f + expf(-s));
            ((u16*)out)[(size_t)p * 512 + n] = f2bf(s);
        }
    }
}

// ---------------------------------------------------------------------------
// spatial kernel: one wave per row of (rows,512) bf16 input.
// rows 0..15487 -> Xb -> skb ; rows 15488..15608 -> Xt (task) -> skt
// out[row*9+k9] = (dot(X[row],w_conv[k9]) + b_conv[k9]) * g_sp[p]/sqrt(1+eps) + b_sp[p]
// ---------------------------------------------------------------------------
__global__ __launch_bounds__(256)
void rowdot9(const u16* __restrict__ Xb, const u16* __restrict__ Xt,
             const float* __restrict__ w_conv, const float* __restrict__ b_conv,
             const float* __restrict__ g_sp, const float* __restrict__ b_sp,
             float* __restrict__ skb, float* __restrict__ skt)
{
    int wid = (blockIdx.x * 256 + threadIdx.x) >> 6;   // global wave id = row
    int lane = threadIdx.x & 63;
    if (wid >= MROWS + SS) return;                      // wave-uniform
    const u16* src = (wid < MROWS) ? Xb + (size_t)wid * 512
                                   : Xt + (size_t)(wid - MROWS) * 512;
    bf16x8 xv = *(const bf16x8*)(src + lane * 8);
    float xf[8];
    #pragma unroll
    for (int j = 0; j < 8; ++j) xf[j] = (float)xv[j];

    float s[9];
    #pragma unroll
    for (int k9 = 0; k9 < 9; ++k9) {
        const float* wr = w_conv + k9 * 512 + lane * 8;
        float4 w0 = *(const float4*)wr;
        float4 w1 = *(const float4*)(wr + 4);
        s[k9] = xf[0] * w0.x + xf[1] * w0.y + xf[2] * w0.z + xf[3] * w0.w
              + xf[4] * w1.x + xf[5] * w1.y + xf[6] * w1.z + xf[7] * w1.w;
    }
    #pragma unroll
    for (int off = 1; off < 64; off <<= 1)
        #pragma unroll
        for (int k9 = 0; k9 < 9; ++k9)
            s[k9] += __shfl_xor(s[k9], off);

    if (lane < 9) {
        int p = wid % 121;
        float v = (s[lane] + b_conv[lane]) * (g_sp[p] * (1.0f / sqrtf(1.0f + BNEPS))) + b_sp[p];
        float* dst = (wid < MROWS) ? skb + (size_t)wid * 9 : skt + (size_t)(wid - MROWS) * 9;
        dst[lane] = v;
    }
}

// ---------------------------------------------------------------------------
// DCT pooling over (rows,512) bf16 input; thread = g*512+c, g==128 -> task.
// y[g*512+c] = sum_p X[(g*121+p)*512+c] * dctT[p*512+c]
// ---------------------------------------------------------------------------
__global__ void dct_pool_xb(const u16* __restrict__ Xb, const u16* __restrict__ Xt,
                            const float* __restrict__ dctT,
                            float* __restrict__ ybuf, float* __restrict__ y_t)
{
    int idx = blockIdx.x * 256 + threadIdx.x;
    if (idx >= 129 * 512) return;
    int g = idx >> 9, c = idx & 511;
    const u16* src = (g < 128) ? Xb + (size_t)g * 121 * 512 + c : Xt + c;
    float s = 0.f;
    for (int p = 0; p < SS; ++p)
        s += bf2f(src[(size_t)p * 512]) * dctT[p * 512 + c];
    if (g < 128) ybuf[idx] = s; else y_t[c] = s;
}

// fc1 (512->32, relu), 8-way k-split; block per g (g==128 -> task)
__global__ __launch_bounds__(256)
void fc1_fused(const float* __restrict__ ybuf, const float* __restrict__ y_t,
               const float* __restrict__ fc1, float* __restrict__ y2buf,
               float* __restrict__ y2_t)
{
    __shared__ float Als[512];
    int g = blockIdx.x;
    const float* a = (g < 128) ? ybuf + (size_t)g * 512 : y_t;
    for (int i = threadIdx.x; i < 128; i += 256)
        ((float4*)Als)[i] = ((const float4*)a)[i];
    __syncthreads();
    int o = threadIdx.x >> 3, kp = threadIdx.x & 7;
    const float* w = fc1 + (size_t)o * 512;
    float s = 0.f;
    for (int k = kp * 4; k < 512; k += 32) {
        float4 wv = *(const float4*)(w + k);
        float4 av = *(const float4*)(Als + k);
        s += wv.x * av.x + wv.y * av.y + wv.z * av.z + wv.w * av.w;
    }
    s += __shfl_xor(s, 1);
    s += __shfl_xor(s, 2);
    s += __shfl_xor(s, 4);
    if (kp == 0) {
        float v = fmaxf(s, 0.f);
        if (g < 128) y2buf[(size_t)g * 32 + o] = v; else y2_t[o] = v;
    }
}

// fc2 + sigmoid + channel BN; thread per output; g==128 -> task
__global__ void fc2_ck_fused(const float* __restrict__ y2buf, const float* __restrict__ y2_t,
                             const float* __restrict__ fc2,
                             const float* __restrict__ g_ch, const float* __restrict__ b_ch,
                             float* __restrict__ ckbuf, float* __restrict__ ck_t)
{
    int idx = blockIdx.x * 256 + threadIdx.x;
    if (idx >= 129 * CDIM * KK) return;
    int g = idx / (CDIM * KK), o = idx % (CDIM * KK);
    int c = o / KK;
    const float* yb = (g < 128) ? y2buf + (size_t)g * 32 : y2_t;
    const float* w = fc2 + (size_t)o * 32;
    float s = 0.f;
    #pragma unroll
    for (int k = 0; k < 32; ++k) s += yb[k] * w[k];
    s = 1.f / (1.f + expf(-s));
    s = s * (g_ch[c] * (1.0f / sqrtf(1.0f + BNEPS))) + b_ch[c];
    if (g < 128) ckbuf[idx] = s; else ck_t[o] = s;
}

// tk[c*1089 + p*9 + k9] = sk_t[p*9+k9] * ck_t[c*9+k9]
__global__ void task_kernel_write(const float* __restrict__ sk_t, const float* __restrict__ ck_t,
                                  float* __restrict__ tk)
{
    int idx = blockIdx.x * blockDim.x + threadIdx.x;
    if (idx >= CDIM * SS * KK) return;
    int k9 = idx % KK;
    int pc = idx / KK;
    int p = pc % SS, c = pc / SS;
    tk[idx] = sk_t[p * KK + k9] * ck_t[c * KK + k9];
}

// out0[b,c,p] = (1/9) sum_k unfold(x)[...,k] * tk[c,p,k] * sk[b,p,k] * ck[b,c,k] + x[b,c,p]
__global__ void final_kernel(const float* __restrict__ x, const float* __restrict__ tk,
                             const float* __restrict__ sk, const float* __restrict__ ck,
                             float* __restrict__ out0)
{
    int idx = blockIdx.x * blockDim.x + threadIdx.x;
    if (idx >= BDIM_B * CDIM * SS) return;
    int p = idx % SS;
    int bc = idx / SS;
    int c = bc % CDIM, b = bc / CDIM;
    int h = p / 11, w = p % 11;
    const float* xp = x + (size_t)bc * SS;
    const float* tkp = tk + ((size_t)c * SS + p) * KK;
    const float* skp = sk + ((size_t)b * SS + p) * KK;
    const float* ckp = ck + ((size_t)b * CDIM + c) * KK;
    float acc = 0.f;
    #pragma unroll
    for (int di = 0; di < 3; ++di) {
        int hh = h + di - 1;
        #pragma unroll
        for (int dj = 0; dj < 3; ++dj) {
            int ww = w + dj - 1;
            int k = di * 3 + dj;
            float xv = (hh >= 0 && hh < 11 && ww >= 0 && ww < 11) ? xp[hh * 11 + ww] : 0.f;
            acc += xv * tkp[k] * skp[k] * ckp[k];
        }
    }
    out0[idx] = acc * (1.0f / 9.0f) + xp[p];
}

extern "C" void kernel_launch(void* const* d_in, const int* in_sizes, int n_in,
                              void* d_out, int out_size, void* d_ws, size_t ws_size,
                              hipStream_t stream)
{
    const float* x      = (const float*)d_in[0];
    const float* dct_w  = (const float*)d_in[1];
    const float* w_conv = (const float*)d_in[2];
    const float* b_conv = (const float*)d_in[3];
    const float* g_sp   = (const float*)d_in[4];
    const float* b_sp   = (const float*)d_in[5];
    const float* g_ch   = (const float*)d_in[6];
    const float* b_ch   = (const float*)d_in[7];
    const float* fc1    = (const float*)d_in[8];
    const float* fc2    = (const float*)d_in[9];
    const float* up_w1  = (const float*)d_in[10];
    const float* up_b1  = (const float*)d_in[11];
    const float* up_g1  = (const float*)d_in[12];
    const float* up_bb1 = (const float*)d_in[13];
    const float* up_w2  = (const float*)d_in[14];
    const float* up_b2  = (const float*)d_in[15];
    const float* up_g2  = (const float*)d_in[16];
    const float* up_bb2 = (const float*)d_in[17];
    const float* lo_w1  = (const float*)d_in[18];
    const float* lo_b1  = (const float*)d_in[19];
    const float* lo_g1  = (const float*)d_in[20];
    const float* lo_bb1 = (const float*)d_in[21];
    const float* lo_w2  = (const float*)d_in[22];
    const float* lo_b2  = (const float*)d_in[23];
    const float* lo_g2  = (const float*)d_in[24];
    const float* lo_bb2 = (const float*)d_in[25];

    float* out0 = (float*)d_out;                       // (B,C,11,11)
    float* tk   = out0 + (size_t)BDIM_B * CDIM * SS;   // (1,C,11,11,3,3)

    // workspace layout (bytes, 64B-aligned chunks)
    char* ws = (char*)d_ws;
    size_t off = 0;
    auto alloc = [&](size_t bytes) { void* p = ws + off; off += (bytes + 63) & ~(size_t)63; return p; };
    u16*   Xb     = (u16*)alloc((size_t)MROWS * 512 * 2);
    u16*   Y1     = (u16*)alloc((size_t)MROWS * 1024 * 2);
    u16*   w1b    = (u16*)alloc((size_t)1024 * 512 * 2);
    u16*   w2b    = (u16*)alloc((size_t)1024 * 1024 * 2);
    float* asum   = (float*)alloc((size_t)SS * 1024 * 4);
    float* a3     = (float*)alloc((size_t)SS * 1024 * 4);
    u16*   ts_pc  = (u16*)alloc((size_t)SS * 512 * 2);     // task_s in (p,c) bf16
    float* dctT   = (float*)alloc((size_t)SS * 512 * 4);
    float* ybuf   = (float*)alloc((size_t)BDIM_B * CDIM * 4);
    float* y2buf  = (float*)alloc((size_t)BDIM_B * 32 * 4);
    float* ckbuf  = (float*)alloc((size_t)BDIM_B * CDIM * KK * 4);
    float* skbuf  = (float*)alloc((size_t)BDIM_B * SS * KK * 4);
    float* y_t    = (float*)alloc((size_t)CDIM * 4);
    float* y2_t   = (float*)alloc((size_t)32 * 4);
    float* ck_t   = (float*)alloc((size_t)CDIM * KK * 4);
    float* sk_t   = (float*)alloc((size_t)SS * KK * 4);

    // --- prep: bf16 conversions + dct transpose ---
    hipLaunchKernelGGL(transpose_x, dim3(BDIM_B, 8), dim3(256), 0, stream, x, Xb);
    hipLaunchKernelGGL(f32_to_bf16, dim3((1024 * 512 + 255) / 256), dim3(256), 0, stream,
                       up_w1, w1b, 1024 * 512);
    hipLaunchKernelGGL(f32_to_bf16, dim3((1024 * 1024 + 255) / 256), dim3(256), 0, stream,
                       up_w2, w2b, 1024 * 1024);
    hipLaunchKernelGGL(transpose_dct, dim3((512 * 121 + 255) / 256), dim3(256), 0, stream,
                       dct_w, dctT);

    // --- up path: two MFMA GEMMs; batch-sum fused into GEMM2 epilogue ---
    dim3 ggrid(MROWS / 128, 1024 / 128);   // (121, 8)
    hipLaunchKernelGGL((gemm_mfma<1>), ggrid, dim3(256), 0, stream,
                       Xb, w1b, up_b1, up_g1, up_bb1, (void*)Y1, 512);
    hipLaunchKernelGGL((gemm_mfma<2>), ggrid, dim3(256), 0, stream,
                       Y1, w2b, up_b2, up_g2, up_bb2, (void*)asum, 1024);

    // --- lo path: k-split FCs ---
    hipLaunchKernelGGL((fc_ksplit<0>), dim3(SS, 16), dim3(256), 0, stream,
                       asum, lo_w1, lo_b1, lo_g1, lo_bb1, (void*)a3, 1024, 1024);
    hipLaunchKernelGGL((fc_ksplit<1>), dim3(SS, 8), dim3(256), 0, stream,
                       a3, lo_w2, lo_b2, lo_g2, lo_bb2, (void*)ts_pc, 512, 1024);

    // --- spatial kernels (instance + task fused): wave per row ---
    hipLaunchKernelGGL(rowdot9, dim3((MROWS + SS + 3) / 4), dim3(256), 0, stream,
                       Xb, ts_pc, w_conv, b_conv, g_sp, b_sp, skbuf, sk_t);

    // --- channel kernels (instance + task fused) ---
    hipLaunchKernelGGL(dct_pool_xb, dim3((129 * 512) / 256), dim3(256), 0, stream,
                       Xb, ts_pc, dctT, ybuf, y_t);
    hipLaunchKernelGGL(fc1_fused, dim3(129), dim3(256), 0, stream,
                       ybuf, y_t, fc1, y2buf, y2_t);
    hipLaunchKernelGGL(fc2_ck_fused, dim3((129 * CDIM * KK + 255) / 256), dim3(256), 0, stream,
                       y2buf, y2_t, fc2, g_ch, b_ch, ckbuf, ck_t);

    // --- task kernel output ---
    hipLaunchKernelGGL(task_kernel_write, dim3((CDIM * SS * KK + 255) / 256), dim3(256), 0, stream,
                       sk_t, ck_t, tk);

    // --- final fused unfold * kernel mean + residual ---
    hipLaunchKernelGGL(final_kernel, dim3((BDIM_B * CDIM * SS + 255) / 256), dim3(256), 0, stream,
                       x, tk, skbuf, ckbuf, out0);
}

// Round 4
// 352.377 us; speedup vs baseline: 4.6425x; 1.2664x over previous
//
#include <hip/hip_runtime.h>
#include <hip/hip_bf16.h>
#include <math.h>

#define BNEPS 1e-5f
#define BDIM_B 128
#define CDIM 512
#define SS 121
#define KK 9
#define MROWS (BDIM_B * SS)   // 15488

typedef unsigned short u16;
typedef __bf16 bf16x8 __attribute__((ext_vector_type(8)));
typedef float f32x4 __attribute__((ext_vector_type(4)));

__device__ __forceinline__ u16 f2bf(float f) {
    union { float f; unsigned int u; } v; v.f = f;
    unsigned int r = v.u + 0x7FFF + ((v.u >> 16) & 1);   // RNE
    return (u16)(r >> 16);
}
__device__ __forceinline__ float bf2f(u16 v) {
    union { unsigned int u; float f; } x; x.u = ((unsigned int)v) << 16; return x.f;
}

__device__ __forceinline__ void gld16(const u16* g, u16* l) {
    __builtin_amdgcn_global_load_lds(
        (const __attribute__((address_space(1))) void*)g,
        (__attribute__((address_space(3))) void*)l, 16, 0, 0);
}

// ---------------------------------------------------------------------------
// bf16 MFMA GEMM, 128x128 tile, BK=32, 256 threads (4 waves, 2x2 wave grid).
// A: (M,Kd) bf16 row-major.  Bw: (N,Kd) bf16 row-major (B^T form).
// epilogue: v = relu((acc + bias[n]) * g[n]/sqrt(1+eps) + bb[n])
// MODE 1: store bf16 to Yout[(m%121)*128 + m/121][n]   (p-major remap)
// MODE 2: block rows are all one p (p = blockIdx.x); reduce v over the 128
//         rows and store fp32 asum[p*1024 + n]  (fused relu->batch-sum)
// ---------------------------------------------------------------------------
template<int MODE>
__global__ __launch_bounds__(256)
void gemm_mfma(const u16* __restrict__ A, const u16* __restrict__ Bw,
               const float* __restrict__ bias, const float* __restrict__ g,
               const float* __restrict__ bb, void* __restrict__ out, int Kd)
{
    __shared__ __align__(16) u16 Als[128 * 32];
    __shared__ __align__(16) u16 Bls[128 * 32];

    const int tid  = threadIdx.x;
    const int lane = tid & 63;
    const int w    = tid >> 6;
    const int wm   = w >> 1, wn = w & 1;
    const int bm   = blockIdx.x * 128;
    const int bn   = blockIdx.y * 128;

    f32x4 acc[4][4] = {};

    const int subrow = tid >> 2;         // 0..63
    const int kq     = tid & 3;          // 16B chunk within k-row
    const u16* Ab = A  + (size_t)(bm + subrow) * Kd + kq * 8;
    const u16* Bb = Bw + (size_t)(bn + subrow) * Kd + kq * 8;
    u16* Al0 = &Als[(w * 16) * 32];
    u16* Al1 = &Als[(w * 16 + 64) * 32];
    u16* Bl0 = &Bls[(w * 16) * 32];
    u16* Bl1 = &Bls[(w * 16 + 64) * 32];

    const int fa_row = wm * 64 + (lane & 15);
    const int fb_row = wn * 64 + (lane & 15);
    const int kofs   = (lane >> 4) * 8;

    for (int k0 = 0; k0 < Kd; k0 += 32) {
        __syncthreads();
        gld16(Ab + k0, Al0);
        gld16(Ab + (size_t)64 * Kd + k0, Al1);
        gld16(Bb + k0, Bl0);
        gld16(Bb + (size_t)64 * Kd + k0, Bl1);
        __syncthreads();

        bf16x8 af[4], bfv[4];
        #pragma unroll
        for (int i = 0; i < 4; ++i)
            af[i] = *(bf16x8*)&Als[(fa_row + i * 16) * 32 + kofs];
        #pragma unroll
        for (int j = 0; j < 4; ++j)
            bfv[j] = *(bf16x8*)&Bls[(fb_row + j * 16) * 32 + kofs];
        #pragma unroll
        for (int i = 0; i < 4; ++i)
            #pragma unroll
            for (int j = 0; j < 4; ++j)
                acc[i][j] = __builtin_amdgcn_mfma_f32_16x16x32_bf16(af[i], bfv[j], acc[i][j], 0, 0, 0);
    }

    const float inv = 1.0f / sqrtf(1.0f + BNEPS);

    if (MODE == 1) {
        u16* Y = (u16*)out;
        int dstrow[4][4];
        #pragma unroll
        for (int i = 0; i < 4; ++i) {
            int mb = bm + wm * 64 + i * 16 + (lane >> 4) * 4;
            #pragma unroll
            for (int r = 0; r < 4; ++r) {
                int m = mb + r;
                int b = m / 121, p = m - b * 121;
                dstrow[i][r] = p * 128 + b;
            }
        }
        #pragma unroll
        for (int j = 0; j < 4; ++j) {
            int n = bn + wn * 64 + j * 16 + (lane & 15);
            float sc = g[n] * inv, bo = bias[n], bv = bb[n];
            #pragma unroll
            for (int i = 0; i < 4; ++i)
                #pragma unroll
                for (int r = 0; r < 4; ++r) {
                    float v = (acc[i][j][r] + bo) * sc + bv;
                    v = fmaxf(v, 0.0f);
                    Y[(size_t)dstrow[i][r] * 1024 + n] = f2bf(v);
                }
        }
    } else {
        float ps[4];
        #pragma unroll
        for (int j = 0; j < 4; ++j) {
            int n = bn + wn * 64 + j * 16 + (lane & 15);
            float sc = g[n] * inv, bo = bias[n], bv = bb[n];
            float s = 0.f;
            #pragma unroll
            for (int i = 0; i < 4; ++i)
                #pragma unroll
                for (int r = 0; r < 4; ++r) {
                    float v = (acc[i][j][r] + bo) * sc + bv;
                    s += fmaxf(v, 0.0f);
                }
            ps[j] = s;
        }
        __syncthreads();
        float* red = (float*)Als;
        #pragma unroll
        for (int j = 0; j < 4; ++j)
            red[(wm * 4 + (lane >> 4)) * 128 + wn * 64 + j * 16 + (lane & 15)] = ps[j];
        __syncthreads();
        if (tid < 128) {
            float s = 0.f;
            #pragma unroll
            for (int r = 0; r < 8; ++r) s += red[r * 128 + tid];
            ((float*)out)[(size_t)blockIdx.x * 1024 + bn + tid] = s;
        }
    }
}

// x (B,C,11,11) fp32 -> Xb[(b*121+p)*512 + c] bf16  (LDS tile transpose)
__global__ void transpose_x(const float* __restrict__ x, u16* __restrict__ Xb)
{
    __shared__ float t[64 * 121];
    int b = blockIdx.x, c0 = blockIdx.y * 64;
    for (int idx = threadIdx.x; idx < 64 * 121; idx += 256) {
        int c = idx / 121, p = idx - c * 121;
        t[idx] = x[((size_t)b * 512 + c0 + c) * 121 + p];
    }
    __syncthreads();
    for (int idx = threadIdx.x; idx < 121 * 64; idx += 256) {
        int p = idx >> 6, c = idx & 63;
        Xb[((size_t)(b * 121 + p)) * 512 + c0 + c] = f2bf(t[c * 121 + p]);
    }
}

__global__ void f32_to_bf16(const float* __restrict__ in, u16* __restrict__ out, int n)
{
    int i = blockIdx.x * 256 + threadIdx.x;
    if (i < n) out[i] = f2bf(in[i]);
}

// dctT[p*512+c] = dct[c*121+p]
__global__ void transpose_dct(const float* __restrict__ dct, float* __restrict__ dctT)
{
    int idx = blockIdx.x * 256 + threadIdx.x;
    if (idx >= 512 * 121) return;
    int p = idx >> 9, c = idx & 511;
    dctT[idx] = dct[(size_t)c * 121 + p];
}

// ---------------------------------------------------------------------------
// lo-path FC: block = 256 threads computes 64 outputs of row p (4-way k-split).
// ---------------------------------------------------------------------------
template<int ACT>
__global__ __launch_bounds__(256)
void fc_ksplit(const float* __restrict__ A, const float* __restrict__ W,
               const float* __restrict__ bias, const float* __restrict__ g,
               const float* __restrict__ bb, void* __restrict__ out,
               int N, int Kd)
{
    __shared__ float Als[1024];
    int p = blockIdx.x;
    const float* a = A + (size_t)p * Kd;
    for (int i = threadIdx.x; i < Kd / 4; i += 256)
        ((float4*)Als)[i] = ((const float4*)a)[i];
    __syncthreads();
    int n = blockIdx.y * 64 + (threadIdx.x >> 2);
    int kp = threadIdx.x & 3;
    const float* w = W + (size_t)n * Kd;
    float s0 = 0.f, s1 = 0.f;
    for (int k = kp * 4; k < Kd; k += 32) {
        float4 wv = *(const float4*)(w + k);
        float4 av = *(const float4*)(Als + k);
        s0 += wv.x * av.x + wv.y * av.y + wv.z * av.z + wv.w * av.w;
        float4 wv2 = *(const float4*)(w + k + 16);
        float4 av2 = *(const float4*)(Als + k + 16);
        s1 += wv2.x * av2.x + wv2.y * av2.y + wv2.z * av2.z + wv2.w * av2.w;
    }
    float s = s0 + s1;
    s += __shfl_xor(s, 1);
    s += __shfl_xor(s, 2);
    if (kp == 0) {
        s = (s + bias[n]) * (g[n] * (1.0f / sqrtf(1.0f + BNEPS))) + bb[n];
        if (ACT == 0) {
            ((float*)out)[(size_t)p * N + n] = fmaxf(s, 0.f);
        } else {
            s = 1.f / (1.f + expf(-s));
            ((u16*)out)[(size_t)p * 512 + n] = f2bf(s);
        }
    }
}

// ---------------------------------------------------------------------------
// spatial kernel: one wave per row of (rows,512) bf16 input.
// ---------------------------------------------------------------------------
__global__ __launch_bounds__(256)
void rowdot9(const u16* __restrict__ Xb, const u16* __restrict__ Xt,
             const float* __restrict__ w_conv, const float* __restrict__ b_conv,
             const float* __restrict__ g_sp, const float* __restrict__ b_sp,
             float* __restrict__ skb, float* __restrict__ skt)
{
    int wid = (blockIdx.x * 256 + threadIdx.x) >> 6;   // global wave id = row
    int lane = threadIdx.x & 63;
    if (wid >= MROWS + SS) return;                      // wave-uniform
    const u16* src = (wid < MROWS) ? Xb + (size_t)wid * 512
                                   : Xt + (size_t)(wid - MROWS) * 512;
    bf16x8 xv = *(const bf16x8*)(src + lane * 8);
    float xf[8];
    #pragma unroll
    for (int j = 0; j < 8; ++j) xf[j] = (float)xv[j];

    float s[9];
    #pragma unroll
    for (int k9 = 0; k9 < 9; ++k9) {
        const float* wr = w_conv + k9 * 512 + lane * 8;
        float4 w0 = *(const float4*)wr;
        float4 w1 = *(const float4*)(wr + 4);
        s[k9] = xf[0] * w0.x + xf[1] * w0.y + xf[2] * w0.z + xf[3] * w0.w
              + xf[4] * w1.x + xf[5] * w1.y + xf[6] * w1.z + xf[7] * w1.w;
    }
    #pragma unroll
    for (int off = 1; off < 64; off <<= 1)
        #pragma unroll
        for (int k9 = 0; k9 < 9; ++k9)
            s[k9] += __shfl_xor(s[k9], off);

    if (lane < 9) {
        int p = wid % 121;
        float v = (s[lane] + b_conv[lane]) * (g_sp[p] * (1.0f / sqrtf(1.0f + BNEPS))) + b_sp[p];
        float* dst = (wid < MROWS) ? skb + (size_t)wid * 9 : skt + (size_t)(wid - MROWS) * 9;
        dst[lane] = v;
    }
}

// ---------------------------------------------------------------------------
// DCT pooling over (rows,512) bf16 input; thread = g*512+c, g==128 -> task.
// ---------------------------------------------------------------------------
__global__ void dct_pool_xb(const u16* __restrict__ Xb, const u16* __restrict__ Xt,
                            const float* __restrict__ dctT,
                            float* __restrict__ ybuf, float* __restrict__ y_t)
{
    int idx = blockIdx.x * 256 + threadIdx.x;
    if (idx >= 129 * 512) return;
    int g = idx >> 9, c = idx & 511;
    const u16* src = (g < 128) ? Xb + (size_t)g * 121 * 512 + c : Xt + c;
    float s = 0.f;
    for (int p = 0; p < SS; ++p)
        s += bf2f(src[(size_t)p * 512]) * dctT[p * 512 + c];
    if (g < 128) ybuf[idx] = s; else y_t[c] = s;
}

// fc1 (512->32, relu), 8-way k-split; block per g (g==128 -> task)
__global__ __launch_bounds__(256)
void fc1_fused(const float* __restrict__ ybuf, const float* __restrict__ y_t,
               const float* __restrict__ fc1, float* __restrict__ y2buf,
               float* __restrict__ y2_t)
{
    __shared__ float Als[512];
    int g = blockIdx.x;
    const float* a = (g < 128) ? ybuf + (size_t)g * 512 : y_t;
    for (int i = threadIdx.x; i < 128; i += 256)
        ((float4*)Als)[i] = ((const float4*)a)[i];
    __syncthreads();
    int o = threadIdx.x >> 3, kp = threadIdx.x & 7;
    const float* w = fc1 + (size_t)o * 512;
    float s = 0.f;
    for (int k = kp * 4; k < 512; k += 32) {
        float4 wv = *(const float4*)(w + k);
        float4 av = *(const float4*)(Als + k);
        s += wv.x * av.x + wv.y * av.y + wv.z * av.z + wv.w * av.w;
    }
    s += __shfl_xor(s, 1);
    s += __shfl_xor(s, 2);
    s += __shfl_xor(s, 4);
    if (kp == 0) {
        float v = fmaxf(s, 0.f);
        if (g < 128) y2buf[(size_t)g * 32 + o] = v; else y2_t[o] = v;
    }
}

// fc2 + sigmoid + channel BN; thread per output; g==128 -> task
__global__ void fc2_ck_fused(const float* __restrict__ y2buf, const float* __restrict__ y2_t,
                             const float* __restrict__ fc2,
                             const float* __restrict__ g_ch, const float* __restrict__ b_ch,
                             float* __restrict__ ckbuf, float* __restrict__ ck_t)
{
    int idx = blockIdx.x * 256 + threadIdx.x;
    if (idx >= 129 * CDIM * KK) return;
    int g = idx / (CDIM * KK), o = idx % (CDIM * KK);
    int c = o / KK;
    const float* yb = (g < 128) ? y2buf + (size_t)g * 32 : y2_t;
    const float* w = fc2 + (size_t)o * 32;
    float s = 0.f;
    #pragma unroll
    for (int k = 0; k < 32; ++k) s += yb[k] * w[k];
    s = 1.f / (1.f + expf(-s));
    s = s * (g_ch[c] * (1.0f / sqrtf(1.0f + BNEPS))) + b_ch[c];
    if (g < 128) ckbuf[idx] = s; else ck_t[o] = s;
}

// tk[c*1089 + p*9 + k9] = sk_t[p*9+k9] * ck_t[c*9+k9]
__global__ void task_kernel_write(const float* __restrict__ sk_t, const float* __restrict__ ck_t,
                                  float* __restrict__ tk)
{
    int idx = blockIdx.x * blockDim.x + threadIdx.x;
    if (idx >= CDIM * SS * KK) return;
    int k9 = idx % KK;
    int pc = idx / KK;
    int p = pc % SS, c = pc / SS;
    tk[idx] = sk_t[p * KK + k9] * ck_t[c * KK + k9];
}

// ---------------------------------------------------------------------------
// final: out0[b,c,p] = (1/9) sum_k unfold(x)[k] * PS[p,k] * CS[c,k] + x[b,c,p]
// where PS[p,k] = sk[b,p,k]*sk_t[p,k], CS[c,k] = ck[b,c,k]*ck_t[c,k]
// (tk[c,p,k] = sk_t[p,k]*ck_t[c,k] folded in algebraically).
// Block = (b, 64 channels); all global loads coalesced; inner loop LDS-only.
// ---------------------------------------------------------------------------
__global__ __launch_bounds__(256)
void final_v2(const float* __restrict__ x, const float* __restrict__ skb,
              const float* __restrict__ sk_t, const float* __restrict__ ckbuf,
              const float* __restrict__ ck_t, float* __restrict__ out0)
{
    __shared__ float PS[SS * KK];       // 1089 fp32
    __shared__ float CS[64 * KK];       // 576 fp32
    __shared__ float XT[64 * SS];       // 7744 fp32 (64 x-planes)
    const int tid = threadIdx.x;
    const int b = blockIdx.x, c0 = blockIdx.y * 64;

    const float* sp = skb + (size_t)b * SS * KK;
    for (int i = tid; i < SS * KK; i += 256) PS[i] = sp[i] * sk_t[i];
    const float* cp = ckbuf + ((size_t)b * CDIM + c0) * KK;
    const float* tp = ck_t + (size_t)c0 * KK;
    for (int i = tid; i < 64 * KK; i += 256) CS[i] = cp[i] * tp[i];
    const float* xp = x + ((size_t)b * CDIM + c0) * SS;
    for (int i = tid; i < 64 * SS; i += 256) XT[i] = xp[i];
    __syncthreads();

    float* op = out0 + ((size_t)b * CDIM + c0) * SS;
    for (int i = tid; i < 64 * SS; i += 256) {
        int c = i / SS, p = i - c * SS;
        int h = p / 11, w = p - h * 11;
        const float* xc = XT + c * SS;
        const float* ps = PS + p * KK;
        const float* cs = CS + c * KK;
        float acc = 0.f;
        #pragma unroll
        for (int di = 0; di < 3; ++di) {
            int hh = h + di - 1;
            bool hv = (unsigned)hh < 11u;
            #pragma unroll
            for (int dj = 0; dj < 3; ++dj) {
                int ww = w + dj - 1;
                int k = di * 3 + dj;
                float xv = (hv && (unsigned)ww < 11u) ? xc[hh * 11 + ww] : 0.f;
                acc += xv * ps[k] * cs[k];
            }
        }
        op[i] = acc * (1.0f / 9.0f) + xc[p];
    }
}

extern "C" void kernel_launch(void* const* d_in, const int* in_sizes, int n_in,
                              void* d_out, int out_size, void* d_ws, size_t ws_size,
                              hipStream_t stream)
{
    const float* x      = (const float*)d_in[0];
    const float* dct_w  = (const float*)d_in[1];
    const float* w_conv = (const float*)d_in[2];
    const float* b_conv = (const float*)d_in[3];
    const float* g_sp   = (const float*)d_in[4];
    const float* b_sp   = (const float*)d_in[5];
    const float* g_ch   = (const float*)d_in[6];
    const float* b_ch   = (const float*)d_in[7];
    const float* fc1    = (const float*)d_in[8];
    const float* fc2    = (const float*)d_in[9];
    const float* up_w1  = (const float*)d_in[10];
    const float* up_b1  = (const float*)d_in[11];
    const float* up_g1  = (const float*)d_in[12];
    const float* up_bb1 = (const float*)d_in[13];
    const float* up_w2  = (const float*)d_in[14];
    const float* up_b2  = (const float*)d_in[15];
    const float* up_g2  = (const float*)d_in[16];
    const float* up_bb2 = (const float*)d_in[17];
    const float* lo_w1  = (const float*)d_in[18];
    const float* lo_b1  = (const float*)d_in[19];
    const float* lo_g1  = (const float*)d_in[20];
    const float* lo_bb1 = (const float*)d_in[21];
    const float* lo_w2  = (const float*)d_in[22];
    const float* lo_b2  = (const float*)d_in[23];
    const float* lo_g2  = (const float*)d_in[24];
    const float* lo_bb2 = (const float*)d_in[25];

    float* out0 = (float*)d_out;                       // (B,C,11,11)
    float* tk   = out0 + (size_t)BDIM_B * CDIM * SS;   // (1,C,11,11,3,3)

    // workspace layout (bytes, 64B-aligned chunks)
    char* ws = (char*)d_ws;
    size_t off = 0;
    auto alloc = [&](size_t bytes) { void* p = ws + off; off += (bytes + 63) & ~(size_t)63; return p; };
    u16*   Xb     = (u16*)alloc((size_t)MROWS * 512 * 2);
    u16*   Y1     = (u16*)alloc((size_t)MROWS * 1024 * 2);
    u16*   w1b    = (u16*)alloc((size_t)1024 * 512 * 2);
    u16*   w2b    = (u16*)alloc((size_t)1024 * 1024 * 2);
    float* asum   = (float*)alloc((size_t)SS * 1024 * 4);
    float* a3     = (float*)alloc((size_t)SS * 1024 * 4);
    u16*   ts_pc  = (u16*)alloc((size_t)SS * 512 * 2);     // task_s in (p,c) bf16
    float* dctT   = (float*)alloc((size_t)SS * 512 * 4);
    float* ybuf   = (float*)alloc((size_t)BDIM_B * CDIM * 4);
    float* y2buf  = (float*)alloc((size_t)BDIM_B * 32 * 4);
    float* ckbuf  = (float*)alloc((size_t)BDIM_B * CDIM * KK * 4);
    float* skbuf  = (float*)alloc((size_t)BDIM_B * SS * KK * 4);
    float* y_t    = (float*)alloc((size_t)CDIM * 4);
    float* y2_t   = (float*)alloc((size_t)32 * 4);
    float* ck_t   = (float*)alloc((size_t)CDIM * KK * 4);
    float* sk_t   = (float*)alloc((size_t)SS * KK * 4);

    // --- prep: bf16 conversions + dct transpose ---
    hipLaunchKernelGGL(transpose_x, dim3(BDIM_B, 8), dim3(256), 0, stream, x, Xb);
    hipLaunchKernelGGL(f32_to_bf16, dim3((1024 * 512 + 255) / 256), dim3(256), 0, stream,
                       up_w1, w1b, 1024 * 512);
    hipLaunchKernelGGL(f32_to_bf16, dim3((1024 * 1024 + 255) / 256), dim3(256), 0, stream,
                       up_w2, w2b, 1024 * 1024);
    hipLaunchKernelGGL(transpose_dct, dim3((512 * 121 + 255) / 256), dim3(256), 0, stream,
                       dct_w, dctT);

    // --- up path: two MFMA GEMMs; batch-sum fused into GEMM2 epilogue ---
    dim3 ggrid(MROWS / 128, 1024 / 128);   // (121, 8)
    hipLaunchKernelGGL((gemm_mfma<1>), ggrid, dim3(256), 0, stream,
                       Xb, w1b, up_b1, up_g1, up_bb1, (void*)Y1, 512);
    hipLaunchKernelGGL((gemm_mfma<2>), ggrid, dim3(256), 0, stream,
                       Y1, w2b, up_b2, up_g2, up_bb2, (void*)asum, 1024);

    // --- lo path: k-split FCs ---
    hipLaunchKernelGGL((fc_ksplit<0>), dim3(SS, 16), dim3(256), 0, stream,
                       asum, lo_w1, lo_b1, lo_g1, lo_bb1, (void*)a3, 1024, 1024);
    hipLaunchKernelGGL((fc_ksplit<1>), dim3(SS, 8), dim3(256), 0, stream,
                       a3, lo_w2, lo_b2, lo_g2, lo_bb2, (void*)ts_pc, 512, 1024);

    // --- spatial kernels (instance + task fused): wave per row ---
    hipLaunchKernelGGL(rowdot9, dim3((MROWS + SS + 3) / 4), dim3(256), 0, stream,
                       Xb, ts_pc, w_conv, b_conv, g_sp, b_sp, skbuf, sk_t);

    // --- channel kernels (instance + task fused) ---
    hipLaunchKernelGGL(dct_pool_xb, dim3((129 * 512) / 256), dim3(256), 0, stream,
                       Xb, ts_pc, dctT, ybuf, y_t);
    hipLaunchKernelGGL(fc1_fused, dim3(129), dim3(256), 0, stream,
                       ybuf, y_t, fc1, y2buf, y2_t);
    hipLaunchKernelGGL(fc2_ck_fused, dim3((129 * CDIM * KK + 255) / 256), dim3(256), 0, stream,
                       y2buf, y2_t, fc2, g_ch, b_ch, ckbuf, ck_t);

    // --- task kernel output ---
    hipLaunchKernelGGL(task_kernel_write, dim3((CDIM * SS * KK + 255) / 256), dim3(256), 0, stream,
                       sk_t, ck_t, tk);

    // --- final fused: factorized kernel product, LDS-staged ---
    hipLaunchKernelGGL(final_v2, dim3(BDIM_B, 8), dim3(256), 0, stream,
                       x, skbuf, sk_t, ckbuf, ck_t, out0);
}